// Round 9
// baseline (437.415 us; speedup 1.0000x reference)
//
#include <hip/hip_runtime.h>

typedef float f4 __attribute__((ext_vector_type(4)));
typedef float f32x4 __attribute__((ext_vector_type(4)));
typedef short bf16x8 __attribute__((ext_vector_type(8)));
typedef unsigned short u16x8 __attribute__((ext_vector_type(8)));

static __device__ __forceinline__ unsigned short f2bf(float f) {
    unsigned int x = __builtin_bit_cast(unsigned int, f);
    x = (x + 0x7fffu + ((x >> 16) & 1u)) >> 16;
    return (unsigned short)x;
}
static __device__ __forceinline__ float bf2f(unsigned short h) {
    unsigned int x = ((unsigned int)h) << 16;
    return __builtin_bit_cast(float, x);
}

static __device__ __forceinline__ void gll16(const unsigned short* g, unsigned short* l) {
    __builtin_amdgcn_global_load_lds(
        (__attribute__((address_space(1))) void*)(g),
        (__attribute__((address_space(3))) void*)(l), 16, 0, 0);
}

// LDS frag offset (shorts) for row r, true 16B-slot s (involution, both sides)
static __device__ __forceinline__ int fragoff(int r, int s) {
    return r * 32 + ((s ^ ((r >> 1) & 3)) << 3);
}

// ---------------- dependency flags (device-scope release/acquire)
static __device__ __forceinline__ void flag_wait(int* f, int target) {
    while (__hip_atomic_load(f, __ATOMIC_ACQUIRE, __HIP_MEMORY_SCOPE_AGENT) < target)
        __builtin_amdgcn_s_sleep(16);
}
static __device__ __forceinline__ void flag_bump(int* f, int tid) {
    __syncthreads();   // all block stores happen-before the release below
    if (tid == 0)
        __hip_atomic_fetch_add(f, 1, __ATOMIC_RELEASE, __HIP_MEMORY_SCOPE_AGENT);
}

// ---------------- job bodies ----------------

// W_out f32 -> hi/lo planes, one 64-row v-panel (full 1024-col width)
static __device__ __forceinline__ void cvt_panel(
    const float* __restrict__ Wo, unsigned short* __restrict__ Wo_h,
    unsigned short* __restrict__ Wo_l, int c, int tid)
{
    const int base = c * 8192;
    for (int g = tid; g < 8192; g += 256) {
        const int idx = (base + g) * 8;
        f4 a = *(const f4*)(Wo + idx);
        f4 b = *(const f4*)(Wo + idx + 4);
        u16x8 hv, lv;
        float s[8] = { a.x, a.y, a.z, a.w, b.x, b.y, b.z, b.w };
        #pragma unroll
        for (int i = 0; i < 8; ++i) {
            unsigned short h = f2bf(s[i]);
            hv[i] = h;
            lv[i] = f2bf(s[i] - bf2f(h));
        }
        *(u16x8*)(Wo_h + idx) = hv;
        *(u16x8*)(Wo_l + idx) = lv;
    }
}

// stage-1 tile: f32 A,W in (reg-staged + in-staging split-bf16 cvt),
// split-bf16 planes out. 64x64 tile, 2-phase.
static __device__ __forceinline__ void gemm_cvt_tile(
    unsigned short* lds,
    const float* __restrict__ A, const float* __restrict__ W,
    int lda, int ldw, int K, const float* __restrict__ bias,
    unsigned short* __restrict__ Ch, unsigned short* __restrict__ Cl,
    int N, int m0, int n0, int tid)
{
    const int lane = tid & 63;
    const int wid  = tid >> 6;
    const int wr   = wid >> 1, wc = wid & 1;
    const int lrow = lane & 15;
    const int s    = lane >> 4;

    const int row  = tid >> 2, slot = tid & 3;
    const int woff = fragoff(row, slot);
    const float* pA = A + (size_t)(m0 + row) * lda + slot * 8;
    const float* pW = W + (size_t)(n0 + row) * ldw + slot * 8;

    f4 ra0, ra1, rw0, rw1;

#define LOADREGS(k0) do { \
    ra0 = *(const f4*)(pA + (k0));     ra1 = *(const f4*)(pA + (k0) + 4); \
    rw0 = *(const f4*)(pW + (k0));     rw1 = *(const f4*)(pW + (k0) + 4); \
} while (0)

#define CVTWRITE(buf) do { \
    u16x8 ha, la, hw, lw; \
    float sa[8] = { ra0.x, ra0.y, ra0.z, ra0.w, ra1.x, ra1.y, ra1.z, ra1.w }; \
    float sw[8] = { rw0.x, rw0.y, rw0.z, rw0.w, rw1.x, rw1.y, rw1.z, rw1.w }; \
    _Pragma("unroll") \
    for (int i = 0; i < 8; ++i) { \
        unsigned short h = f2bf(sa[i]); \
        ha[i] = h; la[i] = f2bf(sa[i] - bf2f(h)); \
        h = f2bf(sw[i]); \
        hw[i] = h; lw[i] = f2bf(sw[i] - bf2f(h)); \
    } \
    *(u16x8*)&lds[((buf) * 4 + 0) * 2048 + woff] = ha; \
    *(u16x8*)&lds[((buf) * 4 + 1) * 2048 + woff] = la; \
    *(u16x8*)&lds[((buf) * 4 + 2) * 2048 + woff] = hw; \
    *(u16x8*)&lds[((buf) * 4 + 3) * 2048 + woff] = lw; \
} while (0)

    f32x4 acc[2][2];
    #pragma unroll
    for (int i = 0; i < 2; ++i)
        #pragma unroll
        for (int j = 0; j < 2; ++j) acc[i][j] = (f32x4){0.f, 0.f, 0.f, 0.f};

    const int nt = K / 32;

    LOADREGS(0);
    CVTWRITE(0);
    __syncthreads();

    int cur = 0;
    for (int t = 0; t < nt; ++t) {
        if (t + 1 < nt) LOADREGS((t + 1) * 32);

        bf16x8 ah[2], al[2], wh[2], wl[2];
        #pragma unroll
        for (int i = 0; i < 2; ++i) {
            const int ra = wr * 32 + i * 16 + lrow;
            const int rw = wc * 32 + i * 16 + lrow;
            ah[i] = *(const bf16x8*)&lds[(cur * 4 + 0) * 2048 + fragoff(ra, s)];
            al[i] = *(const bf16x8*)&lds[(cur * 4 + 1) * 2048 + fragoff(ra, s)];
            wh[i] = *(const bf16x8*)&lds[(cur * 4 + 2) * 2048 + fragoff(rw, s)];
            wl[i] = *(const bf16x8*)&lds[(cur * 4 + 3) * 2048 + fragoff(rw, s)];
        }
        #pragma unroll
        for (int i = 0; i < 2; ++i)
            #pragma unroll
            for (int j = 0; j < 2; ++j) {
                acc[i][j] = __builtin_amdgcn_mfma_f32_16x16x32_bf16(ah[i], wh[j], acc[i][j], 0, 0, 0);
                acc[i][j] = __builtin_amdgcn_mfma_f32_16x16x32_bf16(ah[i], wl[j], acc[i][j], 0, 0, 0);
                acc[i][j] = __builtin_amdgcn_mfma_f32_16x16x32_bf16(al[i], wh[j], acc[i][j], 0, 0, 0);
            }

        if (t + 1 < nt) {
            CVTWRITE(cur ^ 1);
            __syncthreads();
            cur ^= 1;
        }
    }
#undef LOADREGS
#undef CVTWRITE

    #pragma unroll
    for (int i = 0; i < 2; ++i) {
        const int rbase = m0 + wr * 32 + i * 16 + (lane >> 4) * 4;
        #pragma unroll
        for (int j = 0; j < 2; ++j) {
            const int col = n0 + wc * 32 + j * 16 + (lane & 15);
            const float bv = bias[col];
            #pragma unroll
            for (int r = 0; r < 4; ++r) {
                float v = acc[i][j][r] + bv;
                size_t off = (size_t)(rbase + r) * N + col;
                unsigned short h = f2bf(v);
                Ch[off] = h;
                Cl[off] = f2bf(v - bf2f(h));
            }
        }
    }
}

// stage-2 tile: split-bf16 planes in (DMA-staged), f32 out. 64x64, 2-phase.
static __device__ __forceinline__ void gemm_plane_tile(
    unsigned short* lds,
    const unsigned short* __restrict__ Ah, const unsigned short* __restrict__ Al,
    const unsigned short* __restrict__ Wh, const unsigned short* __restrict__ Wl,
    int lda, int ldw, int K, const float* __restrict__ bias,
    float* __restrict__ Cf, int N, int m0, int n0, int tid)
{
    const int lane = tid & 63;
    const int wid  = tid >> 6;
    const int wr   = wid >> 1, wc = wid & 1;
    const int lrow = lane & 15;
    const int s    = lane >> 4;

    const int srow  = wid * 16 + (lane >> 2);
    const int sslot = (lane & 3) ^ ((srow >> 1) & 3);
    const size_t gA = (size_t)(m0 + srow) * lda + sslot * 8;
    const size_t gW = (size_t)(n0 + srow) * ldw + sslot * 8;

#define STAGE(buf, k0) do { \
    gll16(Ah + gA + (k0), &lds[((buf) * 4 + 0) * 2048 + wid * 512]); \
    gll16(Al + gA + (k0), &lds[((buf) * 4 + 1) * 2048 + wid * 512]); \
    gll16(Wh + gW + (k0), &lds[((buf) * 4 + 2) * 2048 + wid * 512]); \
    gll16(Wl + gW + (k0), &lds[((buf) * 4 + 3) * 2048 + wid * 512]); \
} while (0)

    f32x4 acc[2][2];
    #pragma unroll
    for (int i = 0; i < 2; ++i)
        #pragma unroll
        for (int j = 0; j < 2; ++j) acc[i][j] = (f32x4){0.f, 0.f, 0.f, 0.f};

    const int nt = K / 32;

    STAGE(0, 0);
    asm volatile("s_waitcnt vmcnt(0)" ::: "memory");
    __syncthreads();

    int cur = 0;
    for (int t = 0; t < nt; ++t) {
        if (t + 1 < nt) STAGE(cur ^ 1, (t + 1) * 32);

        bf16x8 ah[2], al[2], wh[2], wl[2];
        #pragma unroll
        for (int i = 0; i < 2; ++i) {
            const int ra = wr * 32 + i * 16 + lrow;
            const int rw = wc * 32 + i * 16 + lrow;
            ah[i] = *(const bf16x8*)&lds[(cur * 4 + 0) * 2048 + fragoff(ra, s)];
            al[i] = *(const bf16x8*)&lds[(cur * 4 + 1) * 2048 + fragoff(ra, s)];
            wh[i] = *(const bf16x8*)&lds[(cur * 4 + 2) * 2048 + fragoff(rw, s)];
            wl[i] = *(const bf16x8*)&lds[(cur * 4 + 3) * 2048 + fragoff(rw, s)];
        }
        #pragma unroll
        for (int i = 0; i < 2; ++i)
            #pragma unroll
            for (int j = 0; j < 2; ++j) {
                acc[i][j] = __builtin_amdgcn_mfma_f32_16x16x32_bf16(ah[i], wh[j], acc[i][j], 0, 0, 0);
                acc[i][j] = __builtin_amdgcn_mfma_f32_16x16x32_bf16(ah[i], wl[j], acc[i][j], 0, 0, 0);
                acc[i][j] = __builtin_amdgcn_mfma_f32_16x16x32_bf16(al[i], wh[j], acc[i][j], 0, 0, 0);
            }

        if (t + 1 < nt) {
            asm volatile("s_waitcnt vmcnt(0)" ::: "memory");
            __syncthreads();
            cur ^= 1;
        }
    }
#undef STAGE

    #pragma unroll
    for (int i = 0; i < 2; ++i) {
        const int rbase = m0 + wr * 32 + i * 16 + (lane >> 4) * 4;
        #pragma unroll
        for (int j = 0; j < 2; ++j) {
            const int col = n0 + wc * 32 + j * 16 + (lane & 15);
            const float bv = bias ? bias[col] : 0.f;
            #pragma unroll
            for (int r = 0; r < 4; ++r)
                Cf[(size_t)(rbase + r) * N + col] = acc[i][j][r] + bv;
        }
    }
}

// stage-3: out[(bt),u,:] = X[bt,:] + Y[(b,u),:], one full bt-row (256 KiB)
static __device__ __forceinline__ void bcast_row(
    const float* __restrict__ X, const float* __restrict__ Y,
    float* __restrict__ out, int bt, int tid)
{
    const int Vq = 256;               // 1024 / 4
    const int b  = bt >> 8;           // T = 256
    const f4* X4 = (const f4*)X;
    const f4* Y4 = (const f4*)Y + (size_t)b * 64 * Vq;
    f4* O4 = (f4*)out + (size_t)bt * 64 * Vq;

    f4 x = X4[(size_t)bt * Vq + tid];
    #pragma unroll 4
    for (int u = 0; u < 64; ++u) {
        f4 y = Y4[u * Vq + tid];
        f4 r = { x.x + y.x, x.y + y.y, x.z + y.z, x.w + y.w };
        __builtin_nontemporal_store(r, &O4[u * Vq + tid]);
    }
}

// ---------------- flag zeroing (fresh per call; ws is not re-poisoned)
__global__ __launch_bounds__(128) void zero_flags(int* flags, int n) {
    if ((int)threadIdx.x < n) flags[threadIdx.x] = 0;
}

// ---------------- persistent fused kernel: job queue + dependency flags
// jobs: [cvt 16][p 64][e 256][Y 128][X 512][bcast 2048] = 3024
__global__ __launch_bounds__(256, 2) void joiner_fused(
    const float* __restrict__ enc, const float* __restrict__ pred,
    const float* __restrict__ W_enc, const float* __restrict__ b_enc,
    const float* __restrict__ W_pred, const float* __restrict__ b_pred,
    const float* __restrict__ W_out, const float* __restrict__ b_out,
    unsigned short* Wo_h, unsigned short* Wo_l,
    unsigned short* e_h, unsigned short* e_l,
    unsigned short* p_h, unsigned short* p_l,
    float* ws_X, float* ws_Y, float* out, int* flags)
{
    __shared__ unsigned short lds[2 * 4 * 2048];   // 32 KiB
    __shared__ int s_job;
    const int tid = threadIdx.x;

    int* job_ctr = flags + 0;
    int* wo_f = flags + 1;    // [16]
    int* p_f  = flags + 17;   // [8]  target 8
    int* e_f  = flags + 25;   // [32] target 8
    int* y_f  = flags + 57;   // [1]  target 128
    int* x_f  = flags + 58;   // [32] target 16

    for (;;) {
        __syncthreads();
        if (tid == 0) s_job = atomicAdd(job_ctr, 1);
        __syncthreads();
        const int job = s_job;
        if (job >= 3024) return;

        if (job < 16) {
            cvt_panel(W_out, Wo_h, Wo_l, job, tid);
            flag_bump(&wo_f[job], tid);
        } else if (job < 80) {                 // p tiles: m=jl/8, n=jl%8
            const int jl = job - 16, m = jl >> 3, n = jl & 7;
            gemm_cvt_tile(lds, pred, W_pred, 640, 640, 640, b_pred,
                          p_h, p_l, 512, m * 64, n * 64, tid);
            flag_bump(&p_f[m], tid);
        } else if (job < 336) {                // e tiles: m=jl/8, n=jl%8
            const int jl = job - 80, m = jl >> 3, n = jl & 7;
            gemm_cvt_tile(lds, enc, W_enc, 512, 512, 512, b_enc,
                          e_h, e_l, 512, m * 64, n * 64, tid);
            flag_bump(&e_f[m], tid);
        } else if (job < 464) {                // Y tiles: n=jl/8, m=jl%8
            const int jl = job - 336, n = jl >> 3, m = jl & 7;
            flag_wait(&p_f[m], 8);
            flag_wait(&wo_f[n], 1);
            gemm_plane_tile(lds, p_h, p_l, Wo_h + 512, Wo_l + 512,
                            512, 1024, 512, nullptr, ws_Y, 1024,
                            m * 64, n * 64, tid);
            flag_bump(y_f, tid);
        } else if (job < 976) {                // X tiles: m=jl/16, n=jl%16
            const int jl = job - 464, m = jl >> 4, n = jl & 15;
            flag_wait(&e_f[m], 8);
            flag_wait(&wo_f[n], 1);
            gemm_plane_tile(lds, e_h, e_l, Wo_h, Wo_l,
                            512, 1024, 512, b_out, ws_X, 1024,
                            m * 64, n * 64, tid);
            flag_bump(&x_f[m], tid);
        } else {                               // bcast rows
            const int bt = job - 976;
            flag_wait(&x_f[bt >> 6], 16);
            flag_wait(y_f, 128);
            bcast_row(ws_X, ws_Y, out, bt, tid);
        }
    }
}

extern "C" void kernel_launch(void* const* d_in, const int* in_sizes, int n_in,
                              void* d_out, int out_size, void* d_ws, size_t ws_size,
                              hipStream_t stream) {
    (void)in_sizes; (void)n_in; (void)out_size; (void)ws_size;

    const int B = 8, T = 256, U = 64;
    const int J = 512, V = 1024;
    const int MT = B * T;   // 2048
    const int MU = B * U;   // 512

    const float* enc    = (const float*)d_in[0];
    const float* pred   = (const float*)d_in[1];
    const float* W_enc  = (const float*)d_in[2];
    const float* b_enc  = (const float*)d_in[3];
    const float* W_pred = (const float*)d_in[4];
    const float* b_pred = (const float*)d_in[5];
    const float* W_out  = (const float*)d_in[6];
    const float* b_out  = (const float*)d_in[7];
    float* out = (float*)d_out;

    const int n_Wo = V * 2 * J;   // 1048576
    const int n_e  = MT * J;      // 1048576
    const int n_p  = MU * J;      // 262144

    unsigned short* w = (unsigned short*)d_ws;
    unsigned short* Wo_h = w;
    unsigned short* Wo_l = Wo_h + n_Wo;
    unsigned short* e_h  = Wo_l + n_Wo;
    unsigned short* e_l  = e_h + n_e;
    unsigned short* p_h  = e_l + n_e;
    unsigned short* p_l  = p_h + n_p;
    float* ws_X = (float*)(p_l + n_p);          // (MT, V)
    float* ws_Y = ws_X + (size_t)MT * V;        // (MU, V)
    int*   flags = (int*)(ws_Y + (size_t)MU * V);

    zero_flags<<<1, 128, 0, stream>>>(flags, 90);
    joiner_fused<<<512, 256, 0, stream>>>(
        enc, pred, W_enc, b_enc, W_pred, b_pred, W_out, b_out,
        Wo_h, Wo_l, e_h, e_l, p_h, p_l, ws_X, ws_Y, out, flags);
}

// Round 10
// 234.879 us; speedup vs baseline: 1.8623x; 1.8623x over previous
//
#include <hip/hip_runtime.h>

typedef float f4 __attribute__((ext_vector_type(4)));
typedef float f32x4 __attribute__((ext_vector_type(4)));
typedef short bf16x8 __attribute__((ext_vector_type(8)));
typedef unsigned short u16x8 __attribute__((ext_vector_type(8)));

static __device__ __forceinline__ unsigned short f2bf(float f) {
    unsigned int x = __builtin_bit_cast(unsigned int, f);
    x = (x + 0x7fffu + ((x >> 16) & 1u)) >> 16;
    return (unsigned short)x;
}
static __device__ __forceinline__ float bf2f(unsigned short h) {
    unsigned int x = ((unsigned int)h) << 16;
    return __builtin_bit_cast(float, x);
}

static __device__ __forceinline__ void gll16(const unsigned short* g, unsigned short* l) {
    __builtin_amdgcn_global_load_lds(
        (__attribute__((address_space(1))) void*)(g),
        (__attribute__((address_space(3))) void*)(l), 16, 0, 0);
}

// LDS frag offset (shorts) for row r, true 16B-slot s (involution, both sides)
static __device__ __forceinline__ int fragoff(int r, int s) {
    return r * 32 + ((s ^ ((r >> 1) & 3)) << 3);
}

// ---------------- dependency flags
// Single-poller: tid0 RELAXED-polls (no cache inv per poll), one ACQUIRE on
// success (syncs-with producer release + invalidates this CU's caches), then
// block barrier. Other threads wait at the barrier: zero memory traffic.
static __device__ __forceinline__ void flag_wait(int* f, int target, int tid) {
    if (tid == 0) {
        while (__hip_atomic_load(f, __ATOMIC_RELAXED, __HIP_MEMORY_SCOPE_AGENT) < target)
            __builtin_amdgcn_s_sleep(64);
        (void)__hip_atomic_load(f, __ATOMIC_ACQUIRE, __HIP_MEMORY_SCOPE_AGENT);
    }
    __syncthreads();
}
static __device__ __forceinline__ void flag_bump(int* f, int tid) {
    __syncthreads();   // all block stores happen-before the release below
    if (tid == 0)
        __hip_atomic_fetch_add(f, 1, __ATOMIC_RELEASE, __HIP_MEMORY_SCOPE_AGENT);
}

// ---------------- job bodies ----------------

// W_out f32 -> hi/lo planes, one 64-row v-panel (full 1024-col width)
static __device__ __forceinline__ void cvt_panel(
    const float* __restrict__ Wo, unsigned short* __restrict__ Wo_h,
    unsigned short* __restrict__ Wo_l, int c, int tid)
{
    const int base = c * 8192;
    for (int g = tid; g < 8192; g += 256) {
        const int idx = (base + g) * 8;
        f4 a = *(const f4*)(Wo + idx);
        f4 b = *(const f4*)(Wo + idx + 4);
        u16x8 hv, lv;
        float s[8] = { a.x, a.y, a.z, a.w, b.x, b.y, b.z, b.w };
        #pragma unroll
        for (int i = 0; i < 8; ++i) {
            unsigned short h = f2bf(s[i]);
            hv[i] = h;
            lv[i] = f2bf(s[i] - bf2f(h));
        }
        *(u16x8*)(Wo_h + idx) = hv;
        *(u16x8*)(Wo_l + idx) = lv;
    }
}

// stage-1 tile: f32 A,W in (reg-staged + in-staging split-bf16 cvt),
// split-bf16 planes out. 64x64 tile, 2-phase.
static __device__ __forceinline__ void gemm_cvt_tile(
    unsigned short* lds,
    const float* __restrict__ A, const float* __restrict__ W,
    int lda, int ldw, int K, const float* __restrict__ bias,
    unsigned short* __restrict__ Ch, unsigned short* __restrict__ Cl,
    int N, int m0, int n0, int tid)
{
    const int lane = tid & 63;
    const int wid  = tid >> 6;
    const int wr   = wid >> 1, wc = wid & 1;
    const int lrow = lane & 15;
    const int s    = lane >> 4;

    const int row  = tid >> 2, slot = tid & 3;
    const int woff = fragoff(row, slot);
    const float* pA = A + (size_t)(m0 + row) * lda + slot * 8;
    const float* pW = W + (size_t)(n0 + row) * ldw + slot * 8;

    f4 ra0, ra1, rw0, rw1;

#define LOADREGS(k0) do { \
    ra0 = *(const f4*)(pA + (k0));     ra1 = *(const f4*)(pA + (k0) + 4); \
    rw0 = *(const f4*)(pW + (k0));     rw1 = *(const f4*)(pW + (k0) + 4); \
} while (0)

#define CVTWRITE(buf) do { \
    u16x8 ha, la, hw, lw; \
    float sa[8] = { ra0.x, ra0.y, ra0.z, ra0.w, ra1.x, ra1.y, ra1.z, ra1.w }; \
    float sw[8] = { rw0.x, rw0.y, rw0.z, rw0.w, rw1.x, rw1.y, rw1.z, rw1.w }; \
    _Pragma("unroll") \
    for (int i = 0; i < 8; ++i) { \
        unsigned short h = f2bf(sa[i]); \
        ha[i] = h; la[i] = f2bf(sa[i] - bf2f(h)); \
        h = f2bf(sw[i]); \
        hw[i] = h; lw[i] = f2bf(sw[i] - bf2f(h)); \
    } \
    *(u16x8*)&lds[((buf) * 4 + 0) * 2048 + woff] = ha; \
    *(u16x8*)&lds[((buf) * 4 + 1) * 2048 + woff] = la; \
    *(u16x8*)&lds[((buf) * 4 + 2) * 2048 + woff] = hw; \
    *(u16x8*)&lds[((buf) * 4 + 3) * 2048 + woff] = lw; \
} while (0)

    f32x4 acc[2][2];
    #pragma unroll
    for (int i = 0; i < 2; ++i)
        #pragma unroll
        for (int j = 0; j < 2; ++j) acc[i][j] = (f32x4){0.f, 0.f, 0.f, 0.f};

    const int nt = K / 32;

    LOADREGS(0);
    CVTWRITE(0);
    __syncthreads();

    int cur = 0;
    for (int t = 0; t < nt; ++t) {
        if (t + 1 < nt) LOADREGS((t + 1) * 32);

        bf16x8 ah[2], al[2], wh[2], wl[2];
        #pragma unroll
        for (int i = 0; i < 2; ++i) {
            const int ra = wr * 32 + i * 16 + lrow;
            const int rw = wc * 32 + i * 16 + lrow;
            ah[i] = *(const bf16x8*)&lds[(cur * 4 + 0) * 2048 + fragoff(ra, s)];
            al[i] = *(const bf16x8*)&lds[(cur * 4 + 1) * 2048 + fragoff(ra, s)];
            wh[i] = *(const bf16x8*)&lds[(cur * 4 + 2) * 2048 + fragoff(rw, s)];
            wl[i] = *(const bf16x8*)&lds[(cur * 4 + 3) * 2048 + fragoff(rw, s)];
        }
        #pragma unroll
        for (int i = 0; i < 2; ++i)
            #pragma unroll
            for (int j = 0; j < 2; ++j) {
                acc[i][j] = __builtin_amdgcn_mfma_f32_16x16x32_bf16(ah[i], wh[j], acc[i][j], 0, 0, 0);
                acc[i][j] = __builtin_amdgcn_mfma_f32_16x16x32_bf16(ah[i], wl[j], acc[i][j], 0, 0, 0);
                acc[i][j] = __builtin_amdgcn_mfma_f32_16x16x32_bf16(al[i], wh[j], acc[i][j], 0, 0, 0);
            }

        if (t + 1 < nt) {
            CVTWRITE(cur ^ 1);
            __syncthreads();
            cur ^= 1;
        }
    }
#undef LOADREGS
#undef CVTWRITE

    #pragma unroll
    for (int i = 0; i < 2; ++i) {
        const int rbase = m0 + wr * 32 + i * 16 + (lane >> 4) * 4;
        #pragma unroll
        for (int j = 0; j < 2; ++j) {
            const int col = n0 + wc * 32 + j * 16 + (lane & 15);
            const float bv = bias[col];
            #pragma unroll
            for (int r = 0; r < 4; ++r) {
                float v = acc[i][j][r] + bv;
                size_t off = (size_t)(rbase + r) * N + col;
                unsigned short h = f2bf(v);
                Ch[off] = h;
                Cl[off] = f2bf(v - bf2f(h));
            }
        }
    }
}

// stage-2 tile: split-bf16 planes in (DMA-staged), f32 out. 64x64, 2-phase.
static __device__ __forceinline__ void gemm_plane_tile(
    unsigned short* lds,
    const unsigned short* __restrict__ Ah, const unsigned short* __restrict__ Al,
    const unsigned short* __restrict__ Wh, const unsigned short* __restrict__ Wl,
    int lda, int ldw, int K, const float* __restrict__ bias,
    float* __restrict__ Cf, int N, int m0, int n0, int tid)
{
    const int lane = tid & 63;
    const int wid  = tid >> 6;
    const int wr   = wid >> 1, wc = wid & 1;
    const int lrow = lane & 15;
    const int s    = lane >> 4;

    const int srow  = wid * 16 + (lane >> 2);
    const int sslot = (lane & 3) ^ ((srow >> 1) & 3);
    const size_t gA = (size_t)(m0 + srow) * lda + sslot * 8;
    const size_t gW = (size_t)(n0 + srow) * ldw + sslot * 8;

#define STAGE(buf, k0) do { \
    gll16(Ah + gA + (k0), &lds[((buf) * 4 + 0) * 2048 + wid * 512]); \
    gll16(Al + gA + (k0), &lds[((buf) * 4 + 1) * 2048 + wid * 512]); \
    gll16(Wh + gW + (k0), &lds[((buf) * 4 + 2) * 2048 + wid * 512]); \
    gll16(Wl + gW + (k0), &lds[((buf) * 4 + 3) * 2048 + wid * 512]); \
} while (0)

    f32x4 acc[2][2];
    #pragma unroll
    for (int i = 0; i < 2; ++i)
        #pragma unroll
        for (int j = 0; j < 2; ++j) acc[i][j] = (f32x4){0.f, 0.f, 0.f, 0.f};

    const int nt = K / 32;

    STAGE(0, 0);
    asm volatile("s_waitcnt vmcnt(0)" ::: "memory");
    __syncthreads();

    int cur = 0;
    for (int t = 0; t < nt; ++t) {
        if (t + 1 < nt) STAGE(cur ^ 1, (t + 1) * 32);

        bf16x8 ah[2], al[2], wh[2], wl[2];
        #pragma unroll
        for (int i = 0; i < 2; ++i) {
            const int ra = wr * 32 + i * 16 + lrow;
            const int rw = wc * 32 + i * 16 + lrow;
            ah[i] = *(const bf16x8*)&lds[(cur * 4 + 0) * 2048 + fragoff(ra, s)];
            al[i] = *(const bf16x8*)&lds[(cur * 4 + 1) * 2048 + fragoff(ra, s)];
            wh[i] = *(const bf16x8*)&lds[(cur * 4 + 2) * 2048 + fragoff(rw, s)];
            wl[i] = *(const bf16x8*)&lds[(cur * 4 + 3) * 2048 + fragoff(rw, s)];
        }
        #pragma unroll
        for (int i = 0; i < 2; ++i)
            #pragma unroll
            for (int j = 0; j < 2; ++j) {
                acc[i][j] = __builtin_amdgcn_mfma_f32_16x16x32_bf16(ah[i], wh[j], acc[i][j], 0, 0, 0);
                acc[i][j] = __builtin_amdgcn_mfma_f32_16x16x32_bf16(ah[i], wl[j], acc[i][j], 0, 0, 0);
                acc[i][j] = __builtin_amdgcn_mfma_f32_16x16x32_bf16(al[i], wh[j], acc[i][j], 0, 0, 0);
            }

        if (t + 1 < nt) {
            asm volatile("s_waitcnt vmcnt(0)" ::: "memory");
            __syncthreads();
            cur ^= 1;
        }
    }
#undef STAGE

    #pragma unroll
    for (int i = 0; i < 2; ++i) {
        const int rbase = m0 + wr * 32 + i * 16 + (lane >> 4) * 4;
        #pragma unroll
        for (int j = 0; j < 2; ++j) {
            const int col = n0 + wc * 32 + j * 16 + (lane & 15);
            const float bv = bias ? bias[col] : 0.f;
            #pragma unroll
            for (int r = 0; r < 4; ++r)
                Cf[(size_t)(rbase + r) * N + col] = acc[i][j][r] + bv;
        }
    }
}

// stage-3: out[(bt),u,:] = X[bt,:] + Y[(b,u),:], one full bt-row (256 KiB)
static __device__ __forceinline__ void bcast_row(
    const float* __restrict__ X, const float* __restrict__ Y,
    float* __restrict__ out, int bt, int tid)
{
    const int Vq = 256;               // 1024 / 4
    const int b  = bt >> 8;           // T = 256
    const f4* X4 = (const f4*)X;
    const f4* Y4 = (const f4*)Y + (size_t)b * 64 * Vq;
    f4* O4 = (f4*)out + (size_t)bt * 64 * Vq;

    f4 x = X4[(size_t)bt * Vq + tid];
    #pragma unroll 4
    for (int u = 0; u < 64; ++u) {
        f4 y = Y4[u * Vq + tid];
        f4 r = { x.x + y.x, x.y + y.y, x.z + y.z, x.w + y.w };
        __builtin_nontemporal_store(r, &O4[u * Vq + tid]);
    }
}

// ---------------- flag zeroing (fresh per call; ws is not re-poisoned)
__global__ __launch_bounds__(128) void zero_flags(int* flags, int n) {
    if ((int)threadIdx.x < n) flags[threadIdx.x] = 0;
}

// ---------------- persistent fused kernel: job queue + dependency flags
// jobs: [cvt 16][p 64][e 256][Y 128][X 512][bcast 512 x 4rows] = 1488
__global__ __launch_bounds__(256, 2) void joiner_fused(
    const float* __restrict__ enc, const float* __restrict__ pred,
    const float* __restrict__ W_enc, const float* __restrict__ b_enc,
    const float* __restrict__ W_pred, const float* __restrict__ b_pred,
    const float* __restrict__ W_out, const float* __restrict__ b_out,
    unsigned short* Wo_h, unsigned short* Wo_l,
    unsigned short* e_h, unsigned short* e_l,
    unsigned short* p_h, unsigned short* p_l,
    float* ws_X, float* ws_Y, float* out, int* flags)
{
    __shared__ unsigned short lds[2 * 4 * 2048];   // 32 KiB
    __shared__ int s_job;
    const int tid = threadIdx.x;

    int* job_ctr = flags + 0;
    int* wo_f = flags + 1;    // [16]
    int* p_f  = flags + 17;   // [8]  target 8
    int* e_f  = flags + 25;   // [32] target 8
    int* y_f  = flags + 57;   // [1]  target 128
    int* x_f  = flags + 58;   // [32] target 16

    for (;;) {
        __syncthreads();
        if (tid == 0) s_job = atomicAdd(job_ctr, 1);
        __syncthreads();
        const int job = s_job;
        if (job >= 1488) return;

        if (job < 16) {
            cvt_panel(W_out, Wo_h, Wo_l, job, tid);
            flag_bump(&wo_f[job], tid);
        } else if (job < 80) {                 // p tiles: m=jl/8, n=jl%8
            const int jl = job - 16, m = jl >> 3, n = jl & 7;
            gemm_cvt_tile(lds, pred, W_pred, 640, 640, 640, b_pred,
                          p_h, p_l, 512, m * 64, n * 64, tid);
            flag_bump(&p_f[m], tid);
        } else if (job < 336) {                // e tiles: m=jl/8, n=jl%8
            const int jl = job - 80, m = jl >> 3, n = jl & 7;
            gemm_cvt_tile(lds, enc, W_enc, 512, 512, 512, b_enc,
                          e_h, e_l, 512, m * 64, n * 64, tid);
            flag_bump(&e_f[m], tid);
        } else if (job < 464) {                // Y tiles: n=jl/8, m=jl%8
            const int jl = job - 336, n = jl >> 3, m = jl & 7;
            flag_wait(&p_f[m], 8, tid);
            flag_wait(&wo_f[n], 1, tid);
            gemm_plane_tile(lds, p_h, p_l, Wo_h + 512, Wo_l + 512,
                            512, 1024, 512, nullptr, ws_Y, 1024,
                            m * 64, n * 64, tid);
            flag_bump(y_f, tid);
        } else if (job < 976) {                // X tiles: m=jl/16, n=jl%16
            const int jl = job - 464, m = jl >> 4, n = jl & 15;
            flag_wait(&e_f[m], 8, tid);
            flag_wait(&wo_f[n], 1, tid);
            gemm_plane_tile(lds, e_h, e_l, Wo_h, Wo_l,
                            512, 1024, 512, b_out, ws_X, 1024,
                            m * 64, n * 64, tid);
            flag_bump(&x_f[m], tid);
        } else {                               // bcast: 4 bt-rows per job
            const int bt0 = (job - 976) * 4;   // rows share panel (4 | 64)
            flag_wait(&x_f[bt0 >> 6], 16, tid);
            flag_wait(y_f, 128, tid);
            bcast_row(ws_X, ws_Y, out, bt0 + 0, tid);
            bcast_row(ws_X, ws_Y, out, bt0 + 1, tid);
            bcast_row(ws_X, ws_Y, out, bt0 + 2, tid);
            bcast_row(ws_X, ws_Y, out, bt0 + 3, tid);
        }
    }
}

extern "C" void kernel_launch(void* const* d_in, const int* in_sizes, int n_in,
                              void* d_out, int out_size, void* d_ws, size_t ws_size,
                              hipStream_t stream) {
    (void)in_sizes; (void)n_in; (void)out_size; (void)ws_size;

    const int B = 8, T = 256, U = 64;
    const int J = 512, V = 1024;
    const int MT = B * T;   // 2048
    const int MU = B * U;   // 512

    const float* enc    = (const float*)d_in[0];
    const float* pred   = (const float*)d_in[1];
    const float* W_enc  = (const float*)d_in[2];
    const float* b_enc  = (const float*)d_in[3];
    const float* W_pred = (const float*)d_in[4];
    const float* b_pred = (const float*)d_in[5];
    const float* W_out  = (const float*)d_in[6];
    const float* b_out  = (const float*)d_in[7];
    float* out = (float*)d_out;

    const int n_Wo = V * 2 * J;   // 1048576
    const int n_e  = MT * J;      // 1048576
    const int n_p  = MU * J;      // 262144

    unsigned short* w = (unsigned short*)d_ws;
    unsigned short* Wo_h = w;
    unsigned short* Wo_l = Wo_h + n_Wo;
    unsigned short* e_h  = Wo_l + n_Wo;
    unsigned short* e_l  = e_h + n_e;
    unsigned short* p_h  = e_l + n_e;
    unsigned short* p_l  = p_h + n_p;
    float* ws_X = (float*)(p_l + n_p);          // (MT, V)
    float* ws_Y = ws_X + (size_t)MT * V;        // (MU, V)
    int*   flags = (int*)(ws_Y + (size_t)MU * V);

    zero_flags<<<1, 128, 0, stream>>>(flags, 90);
    joiner_fused<<<512, 256, 0, stream>>>(
        enc, pred, W_enc, b_enc, W_pred, b_pred, W_out, b_out,
        Wo_h, Wo_l, e_h, e_l, p_h, p_l, ws_X, ws_Y, out, flags);
}

// Round 11
// 137.839 us; speedup vs baseline: 3.1734x; 1.7040x over previous
//
#include <hip/hip_runtime.h>

typedef float f4 __attribute__((ext_vector_type(4)));
typedef float f32x4 __attribute__((ext_vector_type(4)));
typedef short bf16x8 __attribute__((ext_vector_type(8)));
typedef unsigned short u16x8 __attribute__((ext_vector_type(8)));

static __device__ __forceinline__ unsigned short f2bf(float f) {
    unsigned int x = __builtin_bit_cast(unsigned int, f);
    x = (x + 0x7fffu + ((x >> 16) & 1u)) >> 16;
    return (unsigned short)x;
}
static __device__ __forceinline__ float bf2f(unsigned short h) {
    unsigned int x = ((unsigned int)h) << 16;
    return __builtin_bit_cast(float, x);
}

// async 16B global->LDS DMA (LDS dest = wave-uniform base + lane*16)
static __device__ __forceinline__ void gll16(const unsigned short* g, unsigned short* l) {
    __builtin_amdgcn_global_load_lds(
        (__attribute__((address_space(1))) void*)(g),
        (__attribute__((address_space(3))) void*)(l), 16, 0, 0);
}

// LDS frag offset (shorts) for row r, true 16B-slot s (involution, both sides)
static __device__ __forceinline__ int fragoff(int r, int s) {
    return r * 32 + ((s ^ ((r >> 1) & 3)) << 3);
}

// ================= stage 1: merged {e,p} GEMM with in-staging f32->split-bf16
//                   conversion, + W_out conversion blocks in same launch
struct GJobF {
    const float *A, *W;
    int lda, ldw;
    const float* bias;
    unsigned short *Ch, *Cl;
    int N, K, nbx;
};

__global__ __launch_bounds__(256, 3) void gemmcvt64(
    GJobF j0, GJobF j1, int nblk0, int nblk1,
    const float* __restrict__ Wo, unsigned short* __restrict__ Wo_h,
    unsigned short* __restrict__ Wo_l, int nWo8)
{
    __shared__ unsigned short lds[2][4][64 * 32];   // 2 bufs x {Ah,Al,Wh,Wl}

    const int bid = blockIdx.x;
    const int tid = threadIdx.x;

    if (bid >= nblk0 + nblk1) {
        // ---- W_out f32 -> hi/lo planes (grid-stride over 8-elem chunks)
        const int nblkc = (int)gridDim.x - nblk0 - nblk1;
        for (int g = (bid - nblk0 - nblk1) * 256 + tid; g < nWo8; g += nblkc * 256) {
            const int idx = g * 8;
            f4 a = *(const f4*)(Wo + idx);
            f4 b = *(const f4*)(Wo + idx + 4);
            u16x8 hv, lv;
            float s[8] = { a.x, a.y, a.z, a.w, b.x, b.y, b.z, b.w };
            #pragma unroll
            for (int i = 0; i < 8; ++i) {
                unsigned short h = f2bf(s[i]);
                hv[i] = h;
                lv[i] = f2bf(s[i] - bf2f(h));
            }
            *(u16x8*)(Wo_h + idx) = hv;
            *(u16x8*)(Wo_l + idx) = lv;
        }
        return;
    }

    const bool first = bid < nblk0;
    const GJobF J = first ? j0 : j1;
    const int local = first ? bid : bid - nblk0;
    const int m0 = (local % J.nbx) * 64;
    const int n0 = (local / J.nbx) * 64;

    const int lane = tid & 63;
    const int wid  = tid >> 6;
    const int wr   = wid >> 1, wc = wid & 1;
    const int lrow = lane & 15;
    const int s    = lane >> 4;

    // staging map: thread -> (row 0..63, true slot 0..3); swizzled LDS write
    const int row  = tid >> 2, slot = tid & 3;
    const int woff = fragoff(row, slot);
    const float* pA = J.A + (size_t)(m0 + row) * J.lda + slot * 8;
    const float* pW = J.W + (size_t)(n0 + row) * J.ldw + slot * 8;

    f4 ra0, ra1, rw0, rw1;

#define LOADREGS(k0) do { \
    ra0 = *(const f4*)(pA + (k0));     ra1 = *(const f4*)(pA + (k0) + 4); \
    rw0 = *(const f4*)(pW + (k0));     rw1 = *(const f4*)(pW + (k0) + 4); \
} while (0)

#define CVTWRITE(buf) do { \
    u16x8 ha, la, hw, lw; \
    float sa[8] = { ra0.x, ra0.y, ra0.z, ra0.w, ra1.x, ra1.y, ra1.z, ra1.w }; \
    float sw[8] = { rw0.x, rw0.y, rw0.z, rw0.w, rw1.x, rw1.y, rw1.z, rw1.w }; \
    _Pragma("unroll") \
    for (int i = 0; i < 8; ++i) { \
        unsigned short h = f2bf(sa[i]); \
        ha[i] = h; la[i] = f2bf(sa[i] - bf2f(h)); \
        h = f2bf(sw[i]); \
        hw[i] = h; lw[i] = f2bf(sw[i] - bf2f(h)); \
    } \
    *(u16x8*)&lds[buf][0][woff] = ha; \
    *(u16x8*)&lds[buf][1][woff] = la; \
    *(u16x8*)&lds[buf][2][woff] = hw; \
    *(u16x8*)&lds[buf][3][woff] = lw; \
} while (0)

    f32x4 acc[2][2];
    #pragma unroll
    for (int i = 0; i < 2; ++i)
        #pragma unroll
        for (int j = 0; j < 2; ++j) acc[i][j] = (f32x4){0.f, 0.f, 0.f, 0.f};

    const int nt = J.K / 32;

    LOADREGS(0);
    CVTWRITE(0);
    __syncthreads();

    int cur = 0;
    for (int t = 0; t < nt; ++t) {
        if (t + 1 < nt) LOADREGS((t + 1) * 32);

        bf16x8 ah[2], al[2], wh[2], wl[2];
        #pragma unroll
        for (int i = 0; i < 2; ++i) {
            const int ra = wr * 32 + i * 16 + lrow;
            const int rw = wc * 32 + i * 16 + lrow;
            ah[i] = *(const bf16x8*)&lds[cur][0][fragoff(ra, s)];
            al[i] = *(const bf16x8*)&lds[cur][1][fragoff(ra, s)];
            wh[i] = *(const bf16x8*)&lds[cur][2][fragoff(rw, s)];
            wl[i] = *(const bf16x8*)&lds[cur][3][fragoff(rw, s)];
        }
        #pragma unroll
        for (int i = 0; i < 2; ++i)
            #pragma unroll
            for (int j = 0; j < 2; ++j) {
                acc[i][j] = __builtin_amdgcn_mfma_f32_16x16x32_bf16(ah[i], wh[j], acc[i][j], 0, 0, 0);
                acc[i][j] = __builtin_amdgcn_mfma_f32_16x16x32_bf16(ah[i], wl[j], acc[i][j], 0, 0, 0);
                acc[i][j] = __builtin_amdgcn_mfma_f32_16x16x32_bf16(al[i], wh[j], acc[i][j], 0, 0, 0);
            }

        if (t + 1 < nt) {
            CVTWRITE(cur ^ 1);
            __syncthreads();
            cur ^= 1;
        }
    }
#undef LOADREGS
#undef CVTWRITE

    // epilogue: split-bf16 planes out; C/D layout col=lane&15, row=(lane>>4)*4+r
    #pragma unroll
    for (int i = 0; i < 2; ++i) {
        const int rbase = m0 + wr * 32 + i * 16 + (lane >> 4) * 4;
        #pragma unroll
        for (int j = 0; j < 2; ++j) {
            const int col = n0 + wc * 32 + j * 16 + (lane & 15);
            const float bv = J.bias[col];
            #pragma unroll
            for (int r = 0; r < 4; ++r) {
                float v = acc[i][j][r] + bv;
                size_t off = (size_t)(rbase + r) * J.N + col;
                unsigned short h = f2bf(v);
                J.Ch[off] = h;
                J.Cl[off] = f2bf(v - bf2f(h));
            }
        }
    }
}

// ================= stage 2: merged {X,Y} split-bf16 GEMM (planes in, f32 out)
//   3-buffer rotation, depth-2 prefetch, counted vmcnt(4), one barrier/step.
struct GJob {
    const unsigned short *Ah, *Al, *Wh, *Wl;
    int lda, ldw;
    const float* bias;
    float* Cf;
    int N, K, nbx;
};

__global__ __launch_bounds__(256, 3) void gemm64(GJob j0, GJob j1, int nblk0)
{
    __shared__ unsigned short lds[3][4][64 * 32];   // 48 KB -> 3 blocks/CU

    const bool first = (int)blockIdx.x < nblk0;
    const GJob J = first ? j0 : j1;
    const int local = first ? (int)blockIdx.x : (int)blockIdx.x - nblk0;
    const int m0 = (local % J.nbx) * 64;
    const int n0 = (local / J.nbx) * 64;

    const int tid  = threadIdx.x;
    const int lane = tid & 63;
    const int wid  = tid >> 6;
    const int wr   = wid >> 1, wc = wid & 1;
    const int lrow = lane & 15;
    const int s    = lane >> 4;

    // DMA staging: pre-swizzled global source slot, linear LDS dest
    const int srow  = wid * 16 + (lane >> 2);
    const int sslot = (lane & 3) ^ ((srow >> 1) & 3);
    const size_t gA = (size_t)(m0 + srow) * J.lda + sslot * 8;
    const size_t gW = (size_t)(n0 + srow) * J.ldw + sslot * 8;

#define STAGE(buf, k0) do { \
    gll16(J.Ah + gA + (k0), &lds[buf][0][wid * 512]); \
    gll16(J.Al + gA + (k0), &lds[buf][1][wid * 512]); \
    gll16(J.Wh + gW + (k0), &lds[buf][2][wid * 512]); \
    gll16(J.Wl + gW + (k0), &lds[buf][3][wid * 512]); \
} while (0)

    f32x4 acc[2][2];
    #pragma unroll
    for (int i = 0; i < 2; ++i)
        #pragma unroll
        for (int j = 0; j < 2; ++j) acc[i][j] = (f32x4){0.f, 0.f, 0.f, 0.f};

    const int nt = J.K / 32;   // 16 (>= 2)

    STAGE(0, 0);
    STAGE(1, 32);              // 8 outstanding per wave (4 per tile)

    for (int t = 0; t < nt; ++t) {
        // wait for tile t's 4 DMAs; tile t+1's stay in flight (never drain to
        // 0 mid-loop). After barrier, buf (t+2)%3 == (t-1)%3 is reusable.
        if (t < nt - 1) asm volatile("s_waitcnt vmcnt(4)" ::: "memory");
        else            asm volatile("s_waitcnt vmcnt(0)" ::: "memory");
        __builtin_amdgcn_sched_barrier(0);
        __builtin_amdgcn_s_barrier();
        __builtin_amdgcn_sched_barrier(0);

        if (t + 2 < nt) STAGE((t + 2) % 3, (t + 2) * 32);

        const int cur = t % 3;
        bf16x8 ah[2], al[2], wh[2], wl[2];
        #pragma unroll
        for (int i = 0; i < 2; ++i) {
            const int ra = wr * 32 + i * 16 + lrow;
            const int rw = wc * 32 + i * 16 + lrow;
            ah[i] = *(const bf16x8*)&lds[cur][0][fragoff(ra, s)];
            al[i] = *(const bf16x8*)&lds[cur][1][fragoff(ra, s)];
            wh[i] = *(const bf16x8*)&lds[cur][2][fragoff(rw, s)];
            wl[i] = *(const bf16x8*)&lds[cur][3][fragoff(rw, s)];
        }
        #pragma unroll
        for (int i = 0; i < 2; ++i)
            #pragma unroll
            for (int j = 0; j < 2; ++j) {
                acc[i][j] = __builtin_amdgcn_mfma_f32_16x16x32_bf16(ah[i], wh[j], acc[i][j], 0, 0, 0);
                acc[i][j] = __builtin_amdgcn_mfma_f32_16x16x32_bf16(ah[i], wl[j], acc[i][j], 0, 0, 0);
                acc[i][j] = __builtin_amdgcn_mfma_f32_16x16x32_bf16(al[i], wh[j], acc[i][j], 0, 0, 0);
            }
    }
#undef STAGE

    #pragma unroll
    for (int i = 0; i < 2; ++i) {
        const int rbase = m0 + wr * 32 + i * 16 + (lane >> 4) * 4;
        #pragma unroll
        for (int j = 0; j < 2; ++j) {
            const int col = n0 + wc * 32 + j * 16 + (lane & 15);
            const float bv = J.bias ? J.bias[col] : 0.f;
            #pragma unroll
            for (int r = 0; r < 4; ++r)
                J.Cf[(size_t)(rbase + r) * J.N + col] = acc[i][j][r] + bv;
        }
    }
}

// ================= stage 3: out[(b,t),u,:] = X[(b,t),:] + Y[(b,u),:]
__global__ __launch_bounds__(256) void bcast_kernel(
    const float* __restrict__ X, const float* __restrict__ Y,
    float* __restrict__ out, int T, int U)
{
    const int Vq  = 256;           // 1024 / 4
    const int bt  = blockIdx.x;
    const int b   = bt / T;
    const int tid = threadIdx.x;

    const f4* X4 = (const f4*)X;
    const f4* Y4 = (const f4*)Y + (size_t)b * U * Vq;
    f4* O4 = (f4*)out + (size_t)bt * U * Vq;

    f4 x = X4[(size_t)bt * Vq + tid];
    #pragma unroll 4
    for (int u = 0; u < U; ++u) {
        f4 y = Y4[u * Vq + tid];
        f4 r = { x.x + y.x, x.y + y.y, x.z + y.z, x.w + y.w };
        __builtin_nontemporal_store(r, &O4[u * Vq + tid]);
    }
}

extern "C" void kernel_launch(void* const* d_in, const int* in_sizes, int n_in,
                              void* d_out, int out_size, void* d_ws, size_t ws_size,
                              hipStream_t stream) {
    (void)in_sizes; (void)n_in; (void)out_size; (void)ws_size;

    const int B = 8, T = 256, U = 64;
    const int ENC = 512, DEC = 640, J = 512, V = 1024;
    const int MT = B * T;   // 2048
    const int MU = B * U;   // 512

    const float* enc    = (const float*)d_in[0];
    const float* pred   = (const float*)d_in[1];
    const float* W_enc  = (const float*)d_in[2];
    const float* b_enc  = (const float*)d_in[3];
    const float* W_pred = (const float*)d_in[4];
    const float* b_pred = (const float*)d_in[5];
    const float* W_out  = (const float*)d_in[6];
    const float* b_out  = (const float*)d_in[7];
    float* out = (float*)d_out;

    const int n_Wo = V * 2 * J;   // 1048576
    const int n_e  = MT * J;      // 1048576
    const int n_p  = MU * J;      // 262144

    unsigned short* w = (unsigned short*)d_ws;
    unsigned short* Wo_h = w;
    unsigned short* Wo_l = Wo_h + n_Wo;
    unsigned short* e_h  = Wo_l + n_Wo;
    unsigned short* e_l  = e_h + n_e;
    unsigned short* p_h  = e_l + n_e;
    unsigned short* p_l  = p_h + n_p;
    float* ws_X = (float*)(p_l + n_p);          // (MT, V)
    float* ws_Y = ws_X + (size_t)MT * V;        // (MU, V)

    // 1) merged e + p GEMMs with in-staging conversion + W_out cvt blocks
    GJobF je = { enc,  W_enc,  ENC, ENC, b_enc,  e_h, e_l, J, ENC, MT / 64 };
    GJobF jp = { pred, W_pred, DEC, DEC, b_pred, p_h, p_l, J, DEC, MU / 64 };
    const int nbe = (MT / 64) * (J / 64);   // 256
    const int nbp = (MU / 64) * (J / 64);   // 64
    const int ncv = 64;
    gemmcvt64<<<nbe + nbp + ncv, 256, 0, stream>>>(
        je, jp, nbe, nbp, W_out, Wo_h, Wo_l, n_Wo / 8);

    // 2) merged X + Y GEMMs (planes in, f32 out), counted-vmcnt 3-buf pipeline
    GJob jx = { e_h, e_l, Wo_h, Wo_l, J, 2 * J, b_out, ws_X, V, J, MT / 64 };
    GJob jy = { p_h, p_l, Wo_h + J, Wo_l + J, J, 2 * J, nullptr, ws_Y, V, J, MU / 64 };
    const int nbx = (MT / 64) * (V / 64);   // 512
    const int nby = (MU / 64) * (V / 64);   // 128
    gemm64<<<nbx + nby, 256, 0, stream>>>(jx, jy, nbx);

    // 3) out = X broadcast + Y
    bcast_kernel<<<dim3(B * T), 256, 0, stream>>>(ws_X, ws_Y, out, T, U);
}